// Round 3
// baseline (544.112 us; speedup 1.0000x reference)
//
#include <hip/hip_runtime.h>
#include <math.h>

// Problem constants
#define D_ELEMS 25088   // C*H*W = 512*7*7
#define D4      6272    // D_ELEMS / 4
#define N_MEM   2000
#define B_KEYS  32
#define PI_2F   1.570795f   // 3.14159 / 2, matches reference
#define EPSF    1e-8f
#define NSLICE  49          // k-slices for k_dots_mfma (6125 waves, ~24/CU)
#define KSLICE  512         // 25088 / 49
#define KSTEPS  16          // KSLICE / 32
#define NSPLIT  10          // n-splits for k_read (980 blocks, ~15 waves/CU)
#define NPS     200         // N_MEM / NSPLIT = 5 * 40 (ring depth 5, no tail)

using short8 = __attribute__((ext_vector_type(8))) short;   // 8 bf16 A/B frag
using short4v = __attribute__((ext_vector_type(4))) short;
using f32x4  = __attribute__((ext_vector_type(4))) float;   // C/D frag

// ws layout (floats), 2.1 MB total:
//   keyb (bf16 keys, as shorts)   : [0, 401408)
//   dots  [2000][32]              : [401408, 465408)   (atomic-accumulated)
//   mn2   [2000]                  : [465408, 467408)   (atomic-accumulated)
//   knorm [32]                    : [467408, 467440)
//   w     [2000][32]              : [467440, 531440)

__device__ inline short f2bf(float x) {   // fp32 -> bf16 RNE (inputs finite)
    union { float f; unsigned u; } v; v.f = x;
    unsigned r = v.u + 0x7fffu + ((v.u >> 16) & 1u);
    return (short)(r >> 16);
}

// Zero the atomic accumulators: out (802816 f), dots (64000 f), mn2 (2000 f).
// grid 784*256 threads, one float4 each for out (exactly 200704 f4).
__global__ __launch_bounds__(256) void k_zero(float* __restrict__ out,
                                              float* __restrict__ dots,
                                              float* __restrict__ mn2) {
    const int i = blockIdx.x * 256 + threadIdx.x;
    const float4 z = make_float4(0.f, 0.f, 0.f, 0.f);
    ((float4*)out)[i] = z;                      // i < 200704 always
    if (i < 16000) ((float4*)dots)[i] = z;
    if (i < 500)   ((float4*)mn2)[i] = z;
}

// One block per key: convert fp32 -> bf16 AND compute knorm[b]. grid 32x256.
__global__ __launch_bounds__(256) void k_prep(const float* __restrict__ key,
                                              short* __restrict__ keyb,
                                              float* __restrict__ knorm) {
    const int b   = blockIdx.x;
    const int tid = threadIdx.x;
    const float4* K4 = (const float4*)(key + (size_t)b * D_ELEMS);
    short4v* KB4 = (short4v*)keyb + (size_t)b * D4;
    float ks = 0.f;
    for (int i = tid; i < D4; i += 256) {
        const float4 f = K4[i];
        short4v s;
        s[0] = f2bf(f.x); s[1] = f2bf(f.y); s[2] = f2bf(f.z); s[3] = f2bf(f.w);
        KB4[i] = s;
        ks += f.x * f.x + f.y * f.y + f.z * f.z + f.w * f.w;
    }
#pragma unroll
    for (int o = 1; o < 64; o <<= 1) ks += __shfl_xor(ks, o, 64);
    __shared__ float sred[4];
    if ((tid & 63) == 0) sred[tid >> 6] = ks;
    __syncthreads();
    if (tid == 0)
        knorm[b] = fmaxf(sqrtf(sred[0] + sred[1] + sred[2] + sred[3]), EPSF);
}

// dots[n][b] += sum_{k in slice s} key[b][k]*mem[n][k]  (bf16 MFMA, atomic)
// mn2[n]    += sum_{k in slice s} mem[n][k]^2           (fp32, atomic)
// grid: 125 n-tiles x 49 slices = 6125 blocks of 1 wave (~24 waves/CU).
// Depth-1 prefetch with EXPLICIT named registers only (runtime-indexed
// local arrays demote to scratch). Atomic tail replaces dots_part+k_reduce.
__global__ __launch_bounds__(64) void k_dots_mfma(const short* __restrict__ keyb,
                                                  const float* __restrict__ mem,
                                                  float* __restrict__ dots,
                                                  float* __restrict__ mn2) {
    const int nt   = blockIdx.x / NSLICE;     // 0..124
    const int s    = blockIdx.x % NSLICE;     // 0..48
    const int n0   = nt * 16;
    const int lane = threadIdx.x;             // 0..63
    const int quad = lane >> 4;
    const int l16  = lane & 15;
    const int k0   = s * KSLICE + quad * 8;   // this lane's k base (floats)

    const short* a0p = keyb + (size_t)l16 * D_ELEMS + k0;          // keys 0..15
    const short* a1p = keyb + (size_t)(16 + l16) * D_ELEMS + k0;   // keys 16..31
    const float4* bp = (const float4*)(mem + (size_t)(n0 + l16) * D_ELEMS + k0);

    f32x4 acc0 = {0.f, 0.f, 0.f, 0.f};
    f32x4 acc1 = {0.f, 0.f, 0.f, 0.f};
    float msq = 0.f;

    // depth-1 prefetch: loads for step t+1 issue before the cvt+mfma of t
    short8 a0 = *(const short8*)a0p;
    short8 a1 = *(const short8*)a1p;
    float4 f0 = bp[0], f1 = bp[1];

    for (int t = 0; t < KSTEPS; ++t) {
        const short8 a0c = a0, a1c = a1;
        const float4 f0c = f0, f1c = f1;
        if (t + 1 < KSTEPS) {                 // wave-uniform branch
            a0 = *(const short8*)(a0p + (t + 1) * 32);
            a1 = *(const short8*)(a1p + (t + 1) * 32);
            f0 = bp[(t + 1) * 8];
            f1 = bp[(t + 1) * 8 + 1];
        }
        msq += f0c.x * f0c.x + f0c.y * f0c.y + f0c.z * f0c.z + f0c.w * f0c.w
             + f1c.x * f1c.x + f1c.y * f1c.y + f1c.z * f1c.z + f1c.w * f1c.w;
        short8 b;
        b[0] = f2bf(f0c.x); b[1] = f2bf(f0c.y); b[2] = f2bf(f0c.z); b[3] = f2bf(f0c.w);
        b[4] = f2bf(f1c.x); b[5] = f2bf(f1c.y); b[6] = f2bf(f1c.z); b[7] = f2bf(f1c.w);
        acc0 = __builtin_amdgcn_mfma_f32_16x16x32_bf16(a0c, b, acc0, 0, 0, 0);
        acc1 = __builtin_amdgcn_mfma_f32_16x16x32_bf16(a1c, b, acc1, 0, 0, 0);
    }

    // D[row=quad*4+r][col=l16]; row = key index (per m-half), col = n index
    float* dp = dots + (size_t)(n0 + l16) * B_KEYS;
#pragma unroll
    for (int r = 0; r < 4; ++r) {
        atomicAdd(dp + quad * 4 + r,      acc0[r]);
        atomicAdd(dp + 16 + quad * 4 + r, acc1[r]);
    }

    // reduce msq across the 4 quads of each n-row (lanes l16, l16+16, ...)
    msq += __shfl_xor(msq, 16, 64);
    msq += __shfl_xor(msq, 32, 64);
    if (lane < 16) atomicAdd(&mn2[n0 + lane], msq);
}

// per-b: cos -> tan -> softmax over n -> w. knorm precomputed by k_prep.
__global__ __launch_bounds__(512) void k_softmax(const float* __restrict__ knormArr,
                                                 const float* __restrict__ dots,
                                                 const float* __restrict__ mn2,
                                                 float* __restrict__ w) {
    const int b   = blockIdx.x;
    const int tid = threadIdx.x;
    __shared__ float sred[512];
    __shared__ float xbuf[N_MEM];
    const float knorm = knormArr[b];

    float mx = -1e30f;
    for (int n = tid; n < N_MEM; n += 512) {
        const float mn = fmaxf(sqrtf(mn2[n]), EPSF);
        const float x  = __tanf((dots[n * B_KEYS + b] / (knorm * mn)) * PI_2F);
        xbuf[n] = x;
        mx = fmaxf(mx, x);
    }
    sred[tid] = mx;
    __syncthreads();
    for (int o = 256; o; o >>= 1) {
        if (tid < o) sred[tid] = fmaxf(sred[tid], sred[tid + o]);
        __syncthreads();
    }
    mx = sred[0];
    __syncthreads();

    float sm = 0.f;
    for (int n = tid; n < N_MEM; n += 512) {   // cache exp in xbuf (own slots)
        const float e = __expf(xbuf[n] - mx);
        xbuf[n] = e;
        sm += e;
    }
    sred[tid] = sm;
    __syncthreads();
    for (int o = 256; o; o >>= 1) {
        if (tid < o) sred[tid] += sred[tid + o];
        __syncthreads();
    }
    const float inv = 1.f / sred[0];

    for (int n = tid; n < N_MEM; n += 512)
        w[n * B_KEYS + b] = xbuf[n] * inv;
}

// out[b][d] += sum_{n in split s} w[n][b] * mem[n][d]   (atomic accumulate)
// grid: 98 d-blocks x 10 splits = 980 blocks (~15 waves/CU). block 256 = 4
// waves; wave bg owns b-group bg*8..+7; 64 lanes own one float4 d-column
// (coalesced 1KB/load). w staged in a 200-n LDS tile (25.6 KB). Depth-5
// register ring via 5x unroll with NAMED registers mv0..mv4 (200 = 5*40,
// no tail; no runtime-indexed arrays -> no scratch). out pre-zeroed by
// k_zero; 32 atomics/thread at the end replaces partial+k_finish.
__global__ __launch_bounds__(256, 4) void k_read(const float* __restrict__ mem,
                                                 const float* __restrict__ w,
                                                 float* __restrict__ out) {
    const int db   = blockIdx.x % 98;
    const int s    = blockIdx.x / 98;
    const int n0   = s * NPS;
    const int bg   = threadIdx.x >> 6;          // 0..3, b0 = bg*8
    const int lane = threadIdx.x & 63;
    const int d4   = db * 64 + lane;            // float4 column, < 6272

    const float4* M4 = (const float4*)mem;
    const float4* W4 = (const float4*)w;
    __shared__ float4 wls4[NPS * 8];            // 200 n x 32 b = 25.6 KB

    float acc[8][4];
#pragma unroll
    for (int i = 0; i < 8; ++i)
#pragma unroll
        for (int j = 0; j < 4; ++j) acc[i][j] = 0.f;

    for (int i = threadIdx.x; i < NPS * 8; i += 256)
        wls4[i] = W4[(size_t)n0 * 8 + i];
    __syncthreads();

    const float4* mp = M4 + (size_t)n0 * D4 + d4;
    float4 mv0 = mp[0];
    float4 mv1 = mp[(size_t)1 * D4];
    float4 mv2 = mp[(size_t)2 * D4];
    float4 mv3 = mp[(size_t)3 * D4];
    float4 mv4 = mp[(size_t)4 * D4];

#define RD_FMA(K, MV)                                                         \
    {                                                                         \
        const float4 mc = MV;                                                 \
        const int ip = nn + 5 + (K);                                          \
        MV = mp[(size_t)(ip < NPS ? ip : NPS - 1) * D4];                      \
        const float4 wa = wls4[(nn + (K)) * 8 + bg * 2];                      \
        const float4 wb = wls4[(nn + (K)) * 8 + bg * 2 + 1];                  \
        const float wv[8] = {wa.x, wa.y, wa.z, wa.w, wb.x, wb.y, wb.z, wb.w}; \
        _Pragma("unroll")                                                     \
        for (int i = 0; i < 8; ++i) {                                         \
            acc[i][0] += wv[i] * mc.x;                                        \
            acc[i][1] += wv[i] * mc.y;                                        \
            acc[i][2] += wv[i] * mc.z;                                        \
            acc[i][3] += wv[i] * mc.w;                                        \
        }                                                                     \
    }

    for (int nn = 0; nn < NPS; nn += 5) {
        RD_FMA(0, mv0)
        RD_FMA(1, mv1)
        RD_FMA(2, mv2)
        RD_FMA(3, mv3)
        RD_FMA(4, mv4)
    }
#undef RD_FMA

#pragma unroll
    for (int i = 0; i < 8; ++i) {
        float* op = out + (size_t)(bg * 8 + i) * D_ELEMS + (size_t)d4 * 4;
#pragma unroll
        for (int j = 0; j < 4; ++j) atomicAdd(op + j, acc[i][j]);
    }
}

extern "C" void kernel_launch(void* const* d_in, const int* in_sizes, int n_in,
                              void* d_out, int out_size, void* d_ws, size_t ws_size,
                              hipStream_t stream) {
    (void)in_sizes; (void)n_in; (void)out_size; (void)ws_size;
    const float* key = (const float*)d_in[0];
    const float* mem = (const float*)d_in[1];
    float* out = (float*)d_out;
    float* ws  = (float*)d_ws;

    short* keyb  = (short*)ws;          // 802816 shorts = 401408 floats
    float* dots  = ws + 401408;         // 64000 floats
    float* mn2   = ws + 465408;         // 2000 floats
    float* knorm = ws + 467408;         // 32 floats
    float* w     = ws + 467440;         // 64000 floats (16B aligned)

    k_zero     <<<784, 256, 0, stream>>>(out, dots, mn2);
    k_prep     <<<B_KEYS, 256, 0, stream>>>(key, keyb, knorm);
    k_dots_mfma<<<125 * NSLICE, 64, 0, stream>>>(keyb, mem, dots, mn2);
    k_softmax  <<<B_KEYS, 512, 0, stream>>>(knorm, dots, mn2, w);
    k_read     <<<98 * NSPLIT, 256, 0, stream>>>(mem, w, out);
}

// Round 4
// 468.431 us; speedup vs baseline: 1.1616x; 1.1616x over previous
//
#include <hip/hip_runtime.h>
#include <hip/hip_bf16.h>
#include <math.h>

// Problem constants
#define D_ELEMS 25088   // C*H*W = 512*7*7
#define D4      6272    // D_ELEMS / 4
#define N_MEM   2000
#define B_KEYS  32
#define PI_2F   1.570795f   // 3.14159 / 2, matches reference
#define EPSF    1e-8f
#define NSLICE  49          // k-slices for k_dots_mfma (6125 waves, ~24/CU)
#define KSLICE  512         // 25088 / 49
#define KSTEPS  16          // KSLICE / 32
#define NTILE   200         // n-rows per LDS tile in k_read (= NPS at ns=10)

using short8 = __attribute__((ext_vector_type(8))) short;   // 8 bf16 A/B frag
using short4v = __attribute__((ext_vector_type(4))) short;
using f32x4  = __attribute__((ext_vector_type(4))) float;   // C/D frag

// ws layout (floats):
//   keyb (bf16 keys, as shorts)   : [0, 401408)
//   dots_part [49][2000][32]      : [401408, 3537408)
//   mn2_part  [49][2000]          : [3537408, 3635408)
//   dots      [2000][32]          : [3635408, 3699408)
//   mn2       [2000]              : [3699408, 3701408)
//   knorm     [32]                : [3701408, 3701440)
//   w         [2000][32]          : [3701440, 3765440)   (16B aligned)
//   partial [ns][32][25088]       : [3765440, +ns*802816) (16B aligned)

__device__ inline short f2bf(float x) {   // fp32 -> bf16 RNE via HW cvt
    __hip_bfloat16 h = __float2bfloat16(x);
    union { __hip_bfloat16 b; short s; } u; u.b = h;
    return u.s;
}

// One block per key: convert fp32 -> bf16 AND compute knorm[b]. grid 32x256.
__global__ __launch_bounds__(256) void k_prep(const float* __restrict__ key,
                                              short* __restrict__ keyb,
                                              float* __restrict__ knorm) {
    const int b   = blockIdx.x;
    const int tid = threadIdx.x;
    const float4* K4 = (const float4*)(key + (size_t)b * D_ELEMS);
    short4v* KB4 = (short4v*)keyb + (size_t)b * D4;
    float ks = 0.f;
    for (int i = tid; i < D4; i += 256) {
        const float4 f = K4[i];
        short4v s;
        s[0] = f2bf(f.x); s[1] = f2bf(f.y); s[2] = f2bf(f.z); s[3] = f2bf(f.w);
        KB4[i] = s;
        ks += f.x * f.x + f.y * f.y + f.z * f.z + f.w * f.w;
    }
#pragma unroll
    for (int o = 1; o < 64; o <<= 1) ks += __shfl_xor(ks, o, 64);
    __shared__ float sred[4];
    if ((tid & 63) == 0) sred[tid >> 6] = ks;
    __syncthreads();
    if (tid == 0)
        knorm[b] = fmaxf(sqrtf(sred[0] + sred[1] + sred[2] + sred[3]), EPSF);
}

// dots_part[s][n][b] = sum_{k in slice s} key[b][k]*mem[n][k]  (bf16 MFMA)
// mn2_part[s][n]     = sum_{k in slice s} mem[n][k]^2          (fp32)
// grid: 125 n-tiles x 49 slices = 6125 blocks of 1 wave (~24 waves/CU).
// Depth-1 prefetch with EXPLICIT named registers only (runtime-indexed
// local arrays demote to scratch). Plain stores to partials (NO atomics --
// contended fp32 atomics measured ~100x worse in round 3).
__global__ __launch_bounds__(64) void k_dots_mfma(const short* __restrict__ keyb,
                                                  const float* __restrict__ mem,
                                                  float* __restrict__ dots_part,
                                                  float* __restrict__ mn2_part) {
    const int nt   = blockIdx.x / NSLICE;     // 0..124
    const int s    = blockIdx.x % NSLICE;     // 0..48
    const int n0   = nt * 16;
    const int lane = threadIdx.x;             // 0..63
    const int quad = lane >> 4;
    const int l16  = lane & 15;
    const int k0   = s * KSLICE + quad * 8;   // this lane's k base (floats)

    const short* a0p = keyb + (size_t)l16 * D_ELEMS + k0;          // keys 0..15
    const short* a1p = keyb + (size_t)(16 + l16) * D_ELEMS + k0;   // keys 16..31
    const float4* bp = (const float4*)(mem + (size_t)(n0 + l16) * D_ELEMS + k0);

    f32x4 acc0 = {0.f, 0.f, 0.f, 0.f};
    f32x4 acc1 = {0.f, 0.f, 0.f, 0.f};
    float msq = 0.f;

    // depth-1 prefetch: loads for step t+1 issue before the cvt+mfma of t
    short8 a0 = *(const short8*)a0p;
    short8 a1 = *(const short8*)a1p;
    float4 f0 = bp[0], f1 = bp[1];

    for (int t = 0; t < KSTEPS; ++t) {
        const short8 a0c = a0, a1c = a1;
        const float4 f0c = f0, f1c = f1;
        if (t + 1 < KSTEPS) {                 // wave-uniform branch
            a0 = *(const short8*)(a0p + (t + 1) * 32);
            a1 = *(const short8*)(a1p + (t + 1) * 32);
            f0 = bp[(t + 1) * 8];
            f1 = bp[(t + 1) * 8 + 1];
        }
        msq += f0c.x * f0c.x + f0c.y * f0c.y + f0c.z * f0c.z + f0c.w * f0c.w
             + f1c.x * f1c.x + f1c.y * f1c.y + f1c.z * f1c.z + f1c.w * f1c.w;
        short8 b;
        b[0] = f2bf(f0c.x); b[1] = f2bf(f0c.y); b[2] = f2bf(f0c.z); b[3] = f2bf(f0c.w);
        b[4] = f2bf(f1c.x); b[5] = f2bf(f1c.y); b[6] = f2bf(f1c.z); b[7] = f2bf(f1c.w);
        acc0 = __builtin_amdgcn_mfma_f32_16x16x32_bf16(a0c, b, acc0, 0, 0, 0);
        acc1 = __builtin_amdgcn_mfma_f32_16x16x32_bf16(a1c, b, acc1, 0, 0, 0);
    }

    // D[row=quad*4+r][col=l16]; row = key index (per m-half), col = n index
    float* dp = dots_part + (size_t)(s * N_MEM + n0 + l16) * B_KEYS;
#pragma unroll
    for (int r = 0; r < 4; ++r) {
        dp[quad * 4 + r]      = acc0[r];
        dp[16 + quad * 4 + r] = acc1[r];
    }

    // reduce msq across the 4 quads of each n-row (lanes l16, l16+16, ...)
    msq += __shfl_xor(msq, 16, 64);
    msq += __shfl_xor(msq, 32, 64);
    if (lane < 16) mn2_part[s * N_MEM + n0 + lane] = msq;
}

// Collapse the 49 slice partials: dots[n][b], mn2[n]. Coalesced. grid 250.
__global__ __launch_bounds__(256) void k_reduce(const float* __restrict__ dots_part,
                                                const float* __restrict__ mn2_part,
                                                float* __restrict__ dots,
                                                float* __restrict__ mn2) {
    const int gid = blockIdx.x * 256 + threadIdx.x;   // 0..63999
    float ds = 0.f;
#pragma unroll
    for (int s = 0; s < NSLICE; ++s) ds += dots_part[s * (N_MEM * B_KEYS) + gid];
    dots[gid] = ds;
    if (gid < N_MEM) {
        float ms = 0.f;
#pragma unroll
        for (int s = 0; s < NSLICE; ++s) ms += mn2_part[s * N_MEM + gid];
        mn2[gid] = ms;
    }
}

// per-b: cos -> tan -> softmax over n -> w. knorm precomputed by k_prep.
__global__ __launch_bounds__(512) void k_softmax(const float* __restrict__ knormArr,
                                                 const float* __restrict__ dots,
                                                 const float* __restrict__ mn2,
                                                 float* __restrict__ w) {
    const int b   = blockIdx.x;
    const int tid = threadIdx.x;
    __shared__ float sred[512];
    __shared__ float xbuf[N_MEM];
    const float knorm = knormArr[b];

    float mx = -1e30f;
    for (int n = tid; n < N_MEM; n += 512) {
        const float mn = fmaxf(sqrtf(mn2[n]), EPSF);
        const float x  = __tanf((dots[n * B_KEYS + b] / (knorm * mn)) * PI_2F);
        xbuf[n] = x;
        mx = fmaxf(mx, x);
    }
    sred[tid] = mx;
    __syncthreads();
    for (int o = 256; o; o >>= 1) {
        if (tid < o) sred[tid] = fmaxf(sred[tid], sred[tid + o]);
        __syncthreads();
    }
    mx = sred[0];
    __syncthreads();

    float sm = 0.f;
    for (int n = tid; n < N_MEM; n += 512) {   // cache exp in xbuf (own slots)
        const float e = __expf(xbuf[n] - mx);
        xbuf[n] = e;
        sm += e;
    }
    sred[tid] = sm;
    __syncthreads();
    for (int o = 256; o; o >>= 1) {
        if (tid < o) sred[tid] += sred[tid + o];
        __syncthreads();
    }
    const float inv = 1.f / sred[0];

    for (int n = tid; n < N_MEM; n += 512)
        w[n * B_KEYS + b] = xbuf[n] * inv;
}

// partial[s][b][d] = sum_{n in split s} w[n][b] * mem[n][d]
// grid: 98 d-blocks x ns splits. block 256 = 4 waves; wave bg owns b-group
// bg*8..bg*8+7; 64 lanes own one float4 d-column (coalesced 1KB/load).
// w staged in 200-n LDS tiles (25.6 KB). Depth-5 register ring via 5x unroll
// with NAMED registers mv0..mv4 (200 = 5*40, no tail; no runtime-indexed
// arrays -> no scratch). Plain float4 stores to partial (NO atomics).
__global__ __launch_bounds__(256, 4) void k_read(const float* __restrict__ mem,
                                                 const float* __restrict__ w,
                                                 float* __restrict__ partial,
                                                 int nPerS) {
    const int db   = blockIdx.x % 98;
    const int s    = blockIdx.x / 98;
    const int n0   = s * nPerS;
    const int bg   = threadIdx.x >> 6;          // 0..3, b0 = bg*8
    const int lane = threadIdx.x & 63;
    const int d4   = db * 64 + lane;            // float4 column, < 6272

    const float4* M4 = (const float4*)mem;
    const float4* W4 = (const float4*)w;
    __shared__ float4 wls4[NTILE * 8];          // 200 n x 32 b = 25.6 KB

    float acc[8][4];
#pragma unroll
    for (int i = 0; i < 8; ++i)
#pragma unroll
        for (int j = 0; j < 4; ++j) acc[i][j] = 0.f;

    for (int c0 = 0; c0 < nPerS; c0 += NTILE) { // nPerS is a multiple of 200
        __syncthreads();
        for (int i = threadIdx.x; i < NTILE * 8; i += 256)
            wls4[i] = W4[(size_t)(n0 + c0) * 8 + i];
        __syncthreads();

        const float4* mp = M4 + (size_t)(n0 + c0) * D4 + d4;
        float4 mv0 = mp[0];
        float4 mv1 = mp[(size_t)1 * D4];
        float4 mv2 = mp[(size_t)2 * D4];
        float4 mv3 = mp[(size_t)3 * D4];
        float4 mv4 = mp[(size_t)4 * D4];

#define RD_FMA(K, MV)                                                         \
        {                                                                     \
            const float4 mc = MV;                                             \
            const int ip = nn + 5 + (K);                                      \
            MV = mp[(size_t)(ip < NTILE ? ip : NTILE - 1) * D4];              \
            const float4 wa = wls4[(nn + (K)) * 8 + bg * 2];                  \
            const float4 wb = wls4[(nn + (K)) * 8 + bg * 2 + 1];              \
            const float wv[8] = {wa.x, wa.y, wa.z, wa.w, wb.x, wb.y, wb.z, wb.w}; \
            _Pragma("unroll")                                                 \
            for (int i = 0; i < 8; ++i) {                                     \
                acc[i][0] += wv[i] * mc.x;                                    \
                acc[i][1] += wv[i] * mc.y;                                    \
                acc[i][2] += wv[i] * mc.z;                                    \
                acc[i][3] += wv[i] * mc.w;                                    \
            }                                                                 \
        }

        for (int nn = 0; nn < NTILE; nn += 5) {
            RD_FMA(0, mv0)
            RD_FMA(1, mv1)
            RD_FMA(2, mv2)
            RD_FMA(3, mv3)
            RD_FMA(4, mv4)
        }
#undef RD_FMA
    }

    float4* P4 = (float4*)partial;
#pragma unroll
    for (int i = 0; i < 8; ++i)
        P4[(size_t)(s * B_KEYS + bg * 8 + i) * D4 + d4] =
            make_float4(acc[i][0], acc[i][1], acc[i][2], acc[i][3]);
}

__global__ __launch_bounds__(256) void k_finish(const float* __restrict__ partial,
                                                float* __restrict__ out, int ns) {
    const int i = blockIdx.x * 256 + threadIdx.x;   // float4 index, grid 784*256
    const float4* P4 = (const float4*)partial;
    float4 sum = P4[i];
    for (int s = 1; s < ns; ++s) {
        const float4 p = P4[(size_t)s * (B_KEYS * D4) + i];
        sum.x += p.x; sum.y += p.y; sum.z += p.z; sum.w += p.w;
    }
    ((float4*)out)[i] = sum;
}

extern "C" void kernel_launch(void* const* d_in, const int* in_sizes, int n_in,
                              void* d_out, int out_size, void* d_ws, size_t ws_size,
                              hipStream_t stream) {
    (void)in_sizes; (void)n_in; (void)out_size;
    const float* key = (const float*)d_in[0];
    const float* mem = (const float*)d_in[1];
    float* out = (float*)d_out;
    float* ws  = (float*)d_ws;

    short* keyb      = (short*)ws;      // 802816 shorts = 401408 floats
    float* dots_part = ws + 401408;     // 3136000 floats
    float* mn2_part  = ws + 3537408;    // 98000 floats
    float* dots      = ws + 3635408;    // 64000 floats
    float* mn2       = ws + 3699408;    // 2000 floats
    float* knorm     = ws + 3701408;    // 32 floats
    float* w         = ws + 3701440;    // 64000 floats (16B aligned)
    float* part      = ws + 3765440;    // ns * 802816 floats (16B aligned)

    // ns candidates: 10, 5, 2, 1 (nPerS stays a multiple of NTILE=200)
    int ns = 10;
    while (ns > 1 && (size_t)(3765440 + (size_t)ns * 802816) * 4 > ws_size)
        ns = (ns == 10) ? 5 : (ns == 5) ? 2 : 1;
    const int nPerS = N_MEM / ns;

    k_prep     <<<B_KEYS, 256, 0, stream>>>(key, keyb, knorm);
    k_dots_mfma<<<125 * NSLICE, 64, 0, stream>>>(keyb, mem, dots_part, mn2_part);
    k_reduce   <<<250, 256, 0, stream>>>(dots_part, mn2_part, dots, mn2);
    k_softmax  <<<B_KEYS, 512, 0, stream>>>(knorm, dots, mn2, w);
    k_read     <<<98 * ns, 256, 0, stream>>>(mem, w, part, nPerS);
    k_finish   <<<784, 256, 0, stream>>>(part, out, ns);
}

// Round 5
// 375.495 us; speedup vs baseline: 1.4491x; 1.2475x over previous
//
#include <hip/hip_runtime.h>
#include <math.h>

// Problem constants
#define D_ELEMS 25088   // C*H*W = 512*7*7
#define D4      6272    // D_ELEMS / 4
#define N_MEM   2000
#define B_KEYS  32
#define PI_2F   1.570795f   // 3.14159 / 2, matches reference
#define EPSF    1e-8f
#define NSLICE  49          // k-slices for k_dots_mfma (6125 waves, ~24/CU)
#define KSLICE  512         // 25088 / 49
#define KSTEPS  16          // KSLICE / 32
#define NTILE   250         // n-rows per LDS tile in k_read

using short8 = __attribute__((ext_vector_type(8))) short;   // 8 bf16 A/B frag
using short4v = __attribute__((ext_vector_type(4))) short;
using f32x4  = __attribute__((ext_vector_type(4))) float;   // C/D frag

// ws layout (floats):
//   keyb (bf16 keys, as shorts)   : [0, 401408)
//   dots_part [49][2000][32]      : [401408, 3537408)
//   mn2_part  [49][2000]          : [3537408, 3635408)
//   dots      [2000][32]          : [3635408, 3699408)
//   mn2       [2000]              : [3699408, 3701408)
//   knorm     [32]                : [3701408, 3701440)
//   w         [2000][32]          : [3701440, 3765440)   (16B aligned)
//   partial [ns][32][25088]       : [3765440, +ns*802816) (16B aligned)

__device__ inline short f2bf(float x) {   // fp32 -> bf16 RNE (inputs finite)
    union { float f; unsigned u; } v; v.f = x;
    unsigned r = v.u + 0x7fffu + ((v.u >> 16) & 1u);
    return (short)(r >> 16);
}

// One block per key: convert fp32 -> bf16 AND compute knorm[b]. grid 32x256.
__global__ __launch_bounds__(256) void k_prep(const float* __restrict__ key,
                                              short* __restrict__ keyb,
                                              float* __restrict__ knorm) {
    const int b   = blockIdx.x;
    const int tid = threadIdx.x;
    const float4* K4 = (const float4*)(key + (size_t)b * D_ELEMS);
    short4v* KB4 = (short4v*)keyb + (size_t)b * D4;
    float ks = 0.f;
    for (int i = tid; i < D4; i += 256) {
        const float4 f = K4[i];
        short4v s;
        s[0] = f2bf(f.x); s[1] = f2bf(f.y); s[2] = f2bf(f.z); s[3] = f2bf(f.w);
        KB4[i] = s;
        ks += f.x * f.x + f.y * f.y + f.z * f.z + f.w * f.w;
    }
#pragma unroll
    for (int o = 1; o < 64; o <<= 1) ks += __shfl_xor(ks, o, 64);
    __shared__ float sred[4];
    if ((tid & 63) == 0) sred[tid >> 6] = ks;
    __syncthreads();
    if (tid == 0)
        knorm[b] = fmaxf(sqrtf(sred[0] + sred[1] + sred[2] + sred[3]), EPSF);
}

// dots_part[s][n][b] = sum_{k in slice s} key[b][k]*mem[n][k]  (bf16 MFMA)
// mn2_part[s][n]     = sum_{k in slice s} mem[n][k]^2          (fp32)
// grid: 125 n-tiles x 49 slices = 6125 blocks of 1 wave (~24 waves/CU).
// Depth-1 prefetch with EXPLICIT named registers (R1-proven form; hand
// RNE f2bf -- the hip_bf16 cast carries NaN/Inf branches and regressed).
__global__ __launch_bounds__(64) void k_dots_mfma(const short* __restrict__ keyb,
                                                  const float* __restrict__ mem,
                                                  float* __restrict__ dots_part,
                                                  float* __restrict__ mn2_part) {
    const int nt   = blockIdx.x / NSLICE;     // 0..124
    const int s    = blockIdx.x % NSLICE;     // 0..48
    const int n0   = nt * 16;
    const int lane = threadIdx.x;             // 0..63
    const int quad = lane >> 4;
    const int l16  = lane & 15;
    const int k0   = s * KSLICE + quad * 8;   // this lane's k base (floats)

    const short* a0p = keyb + (size_t)l16 * D_ELEMS + k0;          // keys 0..15
    const short* a1p = keyb + (size_t)(16 + l16) * D_ELEMS + k0;   // keys 16..31
    const float4* bp = (const float4*)(mem + (size_t)(n0 + l16) * D_ELEMS + k0);

    f32x4 acc0 = {0.f, 0.f, 0.f, 0.f};
    f32x4 acc1 = {0.f, 0.f, 0.f, 0.f};
    float msq = 0.f;

    // depth-1 prefetch: loads for step t+1 issue before the cvt+mfma of t
    short8 a0 = *(const short8*)a0p;
    short8 a1 = *(const short8*)a1p;
    float4 f0 = bp[0], f1 = bp[1];

    for (int t = 0; t < KSTEPS; ++t) {
        const short8 a0c = a0, a1c = a1;
        const float4 f0c = f0, f1c = f1;
        if (t + 1 < KSTEPS) {                 // wave-uniform branch
            a0 = *(const short8*)(a0p + (t + 1) * 32);
            a1 = *(const short8*)(a1p + (t + 1) * 32);
            f0 = bp[(t + 1) * 8];
            f1 = bp[(t + 1) * 8 + 1];
        }
        msq += f0c.x * f0c.x + f0c.y * f0c.y + f0c.z * f0c.z + f0c.w * f0c.w
             + f1c.x * f1c.x + f1c.y * f1c.y + f1c.z * f1c.z + f1c.w * f1c.w;
        short8 b;
        b[0] = f2bf(f0c.x); b[1] = f2bf(f0c.y); b[2] = f2bf(f0c.z); b[3] = f2bf(f0c.w);
        b[4] = f2bf(f1c.x); b[5] = f2bf(f1c.y); b[6] = f2bf(f1c.z); b[7] = f2bf(f1c.w);
        acc0 = __builtin_amdgcn_mfma_f32_16x16x32_bf16(a0c, b, acc0, 0, 0, 0);
        acc1 = __builtin_amdgcn_mfma_f32_16x16x32_bf16(a1c, b, acc1, 0, 0, 0);
    }

    // D[row=quad*4+r][col=l16]; row = key index (per m-half), col = n index
    float* dp = dots_part + (size_t)(s * N_MEM + n0 + l16) * B_KEYS;
#pragma unroll
    for (int r = 0; r < 4; ++r) {
        dp[quad * 4 + r]      = acc0[r];
        dp[16 + quad * 4 + r] = acc1[r];
    }

    // reduce msq across the 4 quads of each n-row (lanes l16, l16+16, ...)
    msq += __shfl_xor(msq, 16, 64);
    msq += __shfl_xor(msq, 32, 64);
    if (lane < 16) mn2_part[s * N_MEM + n0 + lane] = msq;
}

// Collapse the 49 slice partials: dots[n][b], mn2[n]. Coalesced. grid 250.
__global__ __launch_bounds__(256) void k_reduce(const float* __restrict__ dots_part,
                                                const float* __restrict__ mn2_part,
                                                float* __restrict__ dots,
                                                float* __restrict__ mn2) {
    const int gid = blockIdx.x * 256 + threadIdx.x;   // 0..63999
    float ds = 0.f;
#pragma unroll
    for (int s = 0; s < NSLICE; ++s) ds += dots_part[s * (N_MEM * B_KEYS) + gid];
    dots[gid] = ds;
    if (gid < N_MEM) {
        float ms = 0.f;
#pragma unroll
        for (int s = 0; s < NSLICE; ++s) ms += mn2_part[s * N_MEM + gid];
        mn2[gid] = ms;
    }
}

// per-b: cos -> tan -> softmax over n -> w. knorm precomputed by k_prep.
__global__ __launch_bounds__(512) void k_softmax(const float* __restrict__ knormArr,
                                                 const float* __restrict__ dots,
                                                 const float* __restrict__ mn2,
                                                 float* __restrict__ w) {
    const int b   = blockIdx.x;
    const int tid = threadIdx.x;
    __shared__ float sred[512];
    __shared__ float xbuf[N_MEM];
    const float knorm = knormArr[b];

    float mx = -1e30f;
    for (int n = tid; n < N_MEM; n += 512) {
        const float mn = fmaxf(sqrtf(mn2[n]), EPSF);
        const float x  = __tanf((dots[n * B_KEYS + b] / (knorm * mn)) * PI_2F);
        xbuf[n] = x;
        mx = fmaxf(mx, x);
    }
    sred[tid] = mx;
    __syncthreads();
    for (int o = 256; o; o >>= 1) {
        if (tid < o) sred[tid] = fmaxf(sred[tid], sred[tid + o]);
        __syncthreads();
    }
    mx = sred[0];
    __syncthreads();

    float sm = 0.f;
    for (int n = tid; n < N_MEM; n += 512) {   // cache exp in xbuf (own slots)
        const float e = __expf(xbuf[n] - mx);
        xbuf[n] = e;
        sm += e;
    }
    sred[tid] = sm;
    __syncthreads();
    for (int o = 256; o; o >>= 1) {
        if (tid < o) sred[tid] += sred[tid + o];
        __syncthreads();
    }
    const float inv = 1.f / sred[0];

    for (int n = tid; n < N_MEM; n += 512)
        w[n * B_KEYS + b] = xbuf[n] * inv;
}

// partial[s][b][d] = sum_{n in split s} w[n][b] * mem[n][d]
// grid: 98 d-blocks x ns splits. block 256 = 4 waves; wave bg owns b-group
// bg*8..bg*8+7; 64 lanes own one float4 d-column (coalesced 1KB/load).
// w staged in 250-n LDS tiles (32 KB). PLAIN affine loop + unroll-5:
// R4 proved the manual prefetch ring fights the register allocator
// (VGPR_Count=44 -> ring impossible -> serialized loads, 161us at 10% HBM).
// Let the compiler batch loads with counted vmcnt itself.
__global__ __launch_bounds__(256, 4) void k_read(const float* __restrict__ mem,
                                                 const float* __restrict__ w,
                                                 float* __restrict__ partial,
                                                 int nPerS) {
    const int db   = blockIdx.x % 98;
    const int s    = blockIdx.x / 98;
    const int n0   = s * nPerS;
    const int bg   = threadIdx.x >> 6;          // 0..3, b0 = bg*8
    const int lane = threadIdx.x & 63;
    const int d4   = db * 64 + lane;            // float4 column, < 6272

    const float4* M4 = (const float4*)mem;
    const float4* W4 = (const float4*)w;
    __shared__ float4 wls4[NTILE * 8];          // 250 n x 32 b = 32 KB

    float acc[8][4];
#pragma unroll
    for (int i = 0; i < 8; ++i)
#pragma unroll
        for (int j = 0; j < 4; ++j) acc[i][j] = 0.f;

    for (int c0 = 0; c0 < nPerS; c0 += NTILE) { // nPerS is a multiple of 250
        __syncthreads();
        for (int i = threadIdx.x; i < NTILE * 8; i += 256)
            wls4[i] = W4[(size_t)(n0 + c0) * 8 + i];
        __syncthreads();

        const float4* mp = M4 + (size_t)(n0 + c0) * D4 + d4;
#pragma unroll 5
        for (int nn = 0; nn < NTILE; ++nn) {
            const float4 mc = mp[(size_t)nn * D4];
            const float4 wa = wls4[nn * 8 + bg * 2];
            const float4 wb = wls4[nn * 8 + bg * 2 + 1];
            const float wv[8] = {wa.x, wa.y, wa.z, wa.w, wb.x, wb.y, wb.z, wb.w};
#pragma unroll
            for (int i = 0; i < 8; ++i) {
                acc[i][0] += wv[i] * mc.x;
                acc[i][1] += wv[i] * mc.y;
                acc[i][2] += wv[i] * mc.z;
                acc[i][3] += wv[i] * mc.w;
            }
        }
    }

    float4* P4 = (float4*)partial;
#pragma unroll
    for (int i = 0; i < 8; ++i)
        P4[(size_t)(s * B_KEYS + bg * 8 + i) * D4 + d4] =
            make_float4(acc[i][0], acc[i][1], acc[i][2], acc[i][3]);
}

__global__ __launch_bounds__(256) void k_finish(const float* __restrict__ partial,
                                                float* __restrict__ out, int ns) {
    const int i = blockIdx.x * 256 + threadIdx.x;   // float4 index, grid 784*256
    const float4* P4 = (const float4*)partial;
    float4 sum = P4[i];
    for (int s = 1; s < ns; ++s) {
        const float4 p = P4[(size_t)s * (B_KEYS * D4) + i];
        sum.x += p.x; sum.y += p.y; sum.z += p.z; sum.w += p.w;
    }
    ((float4*)out)[i] = sum;
}

extern "C" void kernel_launch(void* const* d_in, const int* in_sizes, int n_in,
                              void* d_out, int out_size, void* d_ws, size_t ws_size,
                              hipStream_t stream) {
    (void)in_sizes; (void)n_in; (void)out_size;
    const float* key = (const float*)d_in[0];
    const float* mem = (const float*)d_in[1];
    float* out = (float*)d_out;
    float* ws  = (float*)d_ws;

    short* keyb      = (short*)ws;      // 802816 shorts = 401408 floats
    float* dots_part = ws + 401408;     // 3136000 floats
    float* mn2_part  = ws + 3537408;    // 98000 floats
    float* dots      = ws + 3635408;    // 64000 floats
    float* mn2       = ws + 3699408;    // 2000 floats
    float* knorm     = ws + 3701408;    // 32 floats
    float* w         = ws + 3701440;    // 64000 floats (16B aligned)
    float* part      = ws + 3765440;    // ns * 802816 floats (16B aligned)

    // ns candidates: 8, 4, 2, 1 (nPerS stays a multiple of NTILE=250)
    int ns = 8;
    while (ns > 1 && (size_t)(3765440 + (size_t)ns * 802816) * 4 > ws_size) ns >>= 1;
    const int nPerS = N_MEM / ns;

    k_prep     <<<B_KEYS, 256, 0, stream>>>(key, keyb, knorm);
    k_dots_mfma<<<125 * NSLICE, 64, 0, stream>>>(keyb, mem, dots_part, mn2_part);
    k_reduce   <<<250, 256, 0, stream>>>(dots_part, mn2_part, dots, mn2);
    k_softmax  <<<B_KEYS, 512, 0, stream>>>(knorm, dots, mn2, w);
    k_read     <<<98 * ns, 256, 0, stream>>>(mem, w, part, nPerS);
    k_finish   <<<784, 256, 0, stream>>>(part, out, ns);
}